// Round 7
// baseline (261.667 us; speedup 1.0000x reference)
//
#include <hip/hip_runtime.h>
#include <hip/hip_bf16.h>

typedef __bf16 bf16x8 __attribute__((ext_vector_type(8)));
typedef __bf16 bf16x4 __attribute__((ext_vector_type(4)));
typedef float  f32x4  __attribute__((ext_vector_type(4)));

#define NB 4
#define TT 4096
#define CC 1024
#define HH 128
#define MNEG -30000.0f
#define SCALE 0.0450842200278f   // log2(e)/32
#define M0 4.0f                  // fixed softmax shift (exp2 domain)
#define SLOTS_PB 72              // per-batch split-K slots: sum over qt of (qt+2)>>1

__device__ inline void gload16(const void* g, void* l) {
  __builtin_amdgcn_global_load_lds(
      (const __attribute__((address_space(1))) void*)g,
      (__attribute__((address_space(3))) void*)l, 16, 0, 0);
}

// ---------------- dtype probe: bf16 vs fp32 storage ----------------
__global__ void detect_dtype(const unsigned int* __restrict__ xw, int* __restrict__ flag) {
  int t = threadIdx.x;
  int cnt = 0;
#pragma unroll
  for (int i = 0; i < 4; ++i) {
    unsigned int w = xw[t + 64 * i];
    int e = (int)((w >> 7) & 0xFFu);
    cnt += (e >= 100 && e <= 135) ? 1 : 0;
  }
  cnt += __shfl_xor(cnt, 1);  cnt += __shfl_xor(cnt, 2);  cnt += __shfl_xor(cnt, 4);
  cnt += __shfl_xor(cnt, 8);  cnt += __shfl_xor(cnt, 16); cnt += __shfl_xor(cnt, 32);
  if (t == 0) *flag = (cnt >= 128) ? 1 : 0;
}

// -------- transpose W [C][H] -> proj-staging tile format, x3 --------
__global__ __launch_bounds__(256) void transpose_w3(
    const void* __restrict__ Wq, const void* __restrict__ Wk,
    const void* __restrict__ Wv, __bf16* __restrict__ Wt,
    const int* __restrict__ flagp) {
  int isbf = *flagp;
  int which = blockIdx.y;
  const void* W = (which == 0) ? Wq : (which == 1) ? Wk : Wv;
  int idx = blockIdx.x * 256 + threadIdx.x;
  int h = idx >> 10, c = idx & 1023;
  __bf16 val;
  if (isbf) val = ((const __bf16*)W)[c * HH + h];
  else      val = (__bf16)(((const float*)W)[c * HH + h]);
  size_t o = (size_t)(c >> 6) * 24576 + (size_t)which * 8192 +
             (size_t)((c >> 3) & 7) * 1024 + (size_t)h * 8 + (c & 7);
  Wt[o] = val;
}

// ------- fused QKV projection (unchanged from round 6) -------
__global__ __launch_bounds__(768) void qkv_proj(
    const void* __restrict__ x, const __bf16* __restrict__ Wt,
    __bf16* __restrict__ q, __bf16* __restrict__ ktl, __bf16* __restrict__ vtl,
    const int* __restrict__ flagp) {
  __shared__ __align__(16) __bf16 XT[2][4096];
  __shared__ __align__(16) __bf16 WTs[2][24576];
  int isbf = *flagp;
  int tid = threadIdx.x, lane = tid & 63, wave = tid >> 6;
  int which = wave >> 2, rowgrp = wave & 3;
  int l16 = lane & 15, quad = lane >> 4;
  int row0 = blockIdx.x * 64;
  f32x4 acc[8] = {};

#define STAGE(ss, b)                                                          \
  for (int i = wave; i < 56; i += 12) {                                       \
    if (i < 8) {                                                              \
      int row = i * 8 + (lane >> 3), g = lane & 7;                            \
      bf16x8 pk;                                                              \
      if (isbf) {                                                             \
        pk = *(const bf16x8*)((const __bf16*)x + (size_t)(row0 + row) * CC +  \
                              (ss) * 64 + g * 8);                             \
      } else {                                                                \
        const float* xf = (const float*)x + (size_t)(row0 + row) * CC +       \
                          (ss) * 64 + g * 8;                                  \
        f32x4 lo = *(const f32x4*)xf;                                         \
        f32x4 hi = *(const f32x4*)(xf + 4);                                   \
        for (int j = 0; j < 4; ++j) { pk[j] = (__bf16)lo[j]; pk[j+4] = (__bf16)hi[j]; } \
      }                                                                       \
      *(bf16x8*)(&XT[b][g * 512 + (row ^ g) * 8]) = pk;                       \
    } else {                                                                  \
      int j = i - 8;                                                          \
      gload16(Wt + (size_t)(ss) * 24576 + j * 512 + lane * 8,                 \
              &WTs[b][j * 512]);                                              \
    }                                                                         \
  }

  STAGE(0, 0);
  for (int s = 0; s < 16; ++s) {
    int cb = s & 1;
    __syncthreads();
    if (s + 1 < 16) { STAGE(s + 1, cb ^ 1); }
#pragma unroll
    for (int t = 0; t < 2; ++t) {
      int g = t * 4 + quad;
      bf16x8 a = *(const bf16x8*)(&XT[cb][g * 512 + ((rowgrp * 16 + l16) ^ g) * 8]);
#pragma unroll
      for (int nt = 0; nt < 8; ++nt) {
        bf16x8 b = *(const bf16x8*)(&WTs[cb][(size_t)which * 8192 + g * 1024 + (nt * 16 + l16) * 8]);
        acc[nt] = __builtin_amdgcn_mfma_f32_16x16x32_bf16(a, b, acc[nt], 0, 0, 0);
      }
    }
  }
#undef STAGE

  int tile = row0 >> 6;
  if (which == 0) {
#pragma unroll
    for (int nt = 0; nt < 8; ++nt)
#pragma unroll
      for (int r = 0; r < 4; ++r) {
        int row = row0 + rowgrp * 16 + quad * 4 + r;
        q[(size_t)row * HH + nt * 16 + l16] = (__bf16)acc[nt][r];
      }
  } else if (which == 1) {
    __bf16* kb = ktl + (size_t)tile * 8192;
#pragma unroll
    for (int nt = 0; nt < 8; ++nt) {
      int h = nt * 16 + l16, g = h >> 3, j = h & 7;
#pragma unroll
      for (int r = 0; r < 4; ++r) {
        int sidx = rowgrp * 16 + quad * 4 + r;
        kb[g * 512 + sidx * 8 + j] = (__bf16)acc[nt][r];
      }
    }
  } else {
    __bf16* vb = vtl + (size_t)tile * 8192;
#pragma unroll
    for (int nt = 0; nt < 8; ++nt) {
      int h = nt * 16 + l16;
      int sb = rowgrp * 16 + quad * 4;
      bf16x4 pk;
#pragma unroll
      for (int r = 0; r < 4; ++r) pk[r] = (__bf16)acc[nt][r];
      *(bf16x4*)(vb + (sb >> 3) * 1024 + h * 8 + (sb & 7)) = pk;
    }
  }
}

// ------- flash v2: wave=64 q-rows, BR=256/block, LDS ping-pong K+V -------
// K tile [g=h/8][s][8]; V tile [gs=s/8][h][8]; fixed-max softmax (exp2).
__global__ __launch_bounds__(256, 1) void flash_attn(
    const __bf16* __restrict__ q, const __bf16* __restrict__ ktl,
    const __bf16* __restrict__ vtl, __bf16* __restrict__ part,
    float* __restrict__ lml, void* __restrict__ out,
    const int* __restrict__ flagp) {
  __shared__ __align__(16) __bf16 KB[2][8192];   // 32 KB
  __shared__ __align__(16) __bf16 VB[2][8192];   // 32 KB
  __shared__ __align__(16) __bf16 PL[4][64 * 72]; // 36 KB, per-wave P 64x64 (+pad)
  int bx = blockIdx.x;
  int chunk = bx & 7;
  int r = bx >> 3;
  int qt = 15 - (r & 15);               // heavy q-tiles dispatched first
  int batch = r >> 4;
  int nch = (qt + 2) >> 1;              // ceil((4qt+4)/8)
  if (chunk >= nch) return;
  int ntile = 4 * qt + 4;
  int j0 = chunk * 8, j1 = min(j0 + 8, ntile);

  int tid = threadIdx.x, lane = tid & 63, wave = tid >> 6;
  int l16 = lane & 15, quad = lane >> 4;
  int qb = qt * 256;
  const __bf16* qp  = q   + (size_t)batch * TT * HH;
  const __bf16* ktb = ktl + (size_t)batch * TT * HH;
  const __bf16* vtb = vtl + (size_t)batch * TT * HH;

  // Q fragments: 64 rows per wave, A[m=l16][k=quad*8+j], 4 rg x 4 ks
  int qw0 = qb + wave * 64;
  bf16x8 qf[4][4];
#pragma unroll
  for (int rg = 0; rg < 4; ++rg) {
    const __bf16* qrow = qp + (size_t)(qw0 + rg * 16 + l16) * HH + quad * 8;
#pragma unroll
    for (int ks = 0; ks < 4; ++ks) qf[rg][ks] = *(const bf16x8*)(qrow + ks * 32);
  }
  bf16x8 onesf;
#pragma unroll
  for (int j = 0; j < 8; ++j) onesf[j] = (l16 == 0) ? (__bf16)1.0f : (__bf16)0.0f;

  f32x4 acc_o[4][8] = {};
  f32x4 acc_l[4] = {};

  // preload tile j0 into buffer 0
  {
    const __bf16* ksrc = ktb + (size_t)j0 * 8192;
    const __bf16* vsrc = vtb + (size_t)j0 * 8192;
#pragma unroll
    for (int jj = 0; jj < 4; ++jj) {
      int I = wave * 4 + jj;
      gload16(ksrc + I * 512 + lane * 8, &KB[0][I * 512]);
      gload16(vsrc + I * 512 + lane * 8, &VB[0][I * 512]);
    }
  }

  for (int jt = j0; jt < j1; ++jt) {
    int cb = (jt - j0) & 1;
    __syncthreads();                    // drains this iter's staged loads
    if (jt + 1 < j1) {                  // issue next tile; lands during compute
      const __bf16* ksrc = ktb + (size_t)(jt + 1) * 8192;
      const __bf16* vsrc = vtb + (size_t)(jt + 1) * 8192;
#pragma unroll
      for (int jj = 0; jj < 4; ++jj) {
        int I = wave * 4 + jj;
        gload16(ksrc + I * 512 + lane * 8, &KB[cb ^ 1][I * 512]);
        gload16(vsrc + I * 512 + lane * 8, &VB[cb ^ 1][I * 512]);
      }
    }
    const __bf16* Kt = &KB[cb][0];
    const __bf16* Vt = &VB[cb][0];

    // S = Q K^T : 64 rows x 64 cols per wave; 16 kf reads, 64 MFMAs
    f32x4 accs[4][4] = {};              // [rg][sn]
#pragma unroll
    for (int ks = 0; ks < 4; ++ks)
#pragma unroll
      for (int sn = 0; sn < 4; ++sn) {
        bf16x8 kf = *(const bf16x8*)(Kt + ((ks * 4 + quad) * 64 + sn * 16 + l16) * 8);
#pragma unroll
        for (int rg = 0; rg < 4; ++rg)
          accs[rg][sn] = __builtin_amdgcn_mfma_f32_16x16x32_bf16(qf[rg][ks], kf, accs[rg][sn], 0, 0, 0);
      }

    // fixed-max softmax + P write (row-major [64][72] per wave)
    __bf16* pw = &PL[wave][0];
    int band = (jt >= 4 * qt);
    int s0 = jt * 64;
#pragma unroll
    for (int rg = 0; rg < 4; ++rg)
#pragma unroll
      for (int sn = 0; sn < 4; ++sn)
#pragma unroll
        for (int r2 = 0; r2 < 4; ++r2) {
          float z = fmaf(accs[rg][sn][r2], SCALE, -M0);
          if (band) {
            int row = qw0 + rg * 16 + quad * 4 + r2;
            int col = s0 + sn * 16 + l16;
            z = (col <= row) ? z : MNEG;
          }
          pw[(rg * 16 + quad * 4 + r2) * 72 + sn * 16 + l16] = (__bf16)exp2f(z);
        }

    // O += P V ; l += P * ones.  8 pa + 16 vf reads, 72 MFMAs
#pragma unroll
    for (int ks2 = 0; ks2 < 2; ++ks2) {
      bf16x8 pa[4];
#pragma unroll
      for (int rg = 0; rg < 4; ++rg) {
        pa[rg] = *(const bf16x8*)(pw + (rg * 16 + l16) * 72 + ks2 * 32 + quad * 8);
        acc_l[rg] = __builtin_amdgcn_mfma_f32_16x16x32_bf16(pa[rg], onesf, acc_l[rg], 0, 0, 0);
      }
#pragma unroll
      for (int nh = 0; nh < 8; ++nh) {
        bf16x8 vf = *(const bf16x8*)(Vt + ((ks2 * 4 + quad) * 128 + nh * 16 + l16) * 8);
#pragma unroll
        for (int rg = 0; rg < 4; ++rg)
          acc_o[rg][nh] = __builtin_amdgcn_mfma_f32_16x16x32_bf16(pa[rg], vf, acc_o[rg][nh], 0, 0, 0);
      }
    }
  }

  if (nch == 1) {                       // qt <= 1: whole row range, direct out
    int isbf = *flagp;
    __bf16* ob = (__bf16*)out + (size_t)batch * TT * HH;
    float*  of = (float*)out + (size_t)batch * TT * HH;
#pragma unroll
    for (int rg = 0; rg < 4; ++rg)
#pragma unroll
      for (int r2 = 0; r2 < 4; ++r2) {
        float lr = __shfl(acc_l[rg][r2], lane & 48);   // broadcast col0 of quad
        float inv = 1.f / fmaxf(lr, 1e-30f);
        int row = qw0 + rg * 16 + quad * 4 + r2;
#pragma unroll
        for (int nh = 0; nh < 8; ++nh) {
          float val = acc_o[rg][nh][r2] * inv;
          size_t idx = (size_t)row * HH + nh * 16 + l16;
          if (isbf) ob[idx] = (__bf16)val;
          else      of[idx] = val;
        }
      }
  } else {                              // bf16 unnormalized partials (fixed max)
    int ps = 0;
    for (int j = 0; j < qt; ++j) ps += (j + 2) >> 1;
    int slot = batch * SLOTS_PB + ps + chunk;
    __bf16* po = part + (size_t)slot * 32768 + wave * 64 * 128;
#pragma unroll
    for (int rg = 0; rg < 4; ++rg)
#pragma unroll
      for (int nh = 0; nh < 8; ++nh)
#pragma unroll
        for (int r2 = 0; r2 < 4; ++r2)
          po[(rg * 16 + quad * 4 + r2) * 128 + nh * 16 + l16] = (__bf16)acc_o[rg][nh][r2];
    float* pl = lml + (size_t)slot * 256 + wave * 64;
    if (l16 == 0) {
#pragma unroll
      for (int rg = 0; rg < 4; ++rg)
#pragma unroll
        for (int r2 = 0; r2 < 4; ++r2)
          pl[rg * 16 + quad * 4 + r2] = acc_l[rg][r2];
    }
  }
}

// ---------------- combine: sum bf16 partials, divide by sum-l ----------------
__global__ __launch_bounds__(256) void combine(
    const __bf16* __restrict__ part, const float* __restrict__ lml,
    void* __restrict__ out, const int* __restrict__ flagp) {
  int bx = blockIdx.x;                  // batch*16 + qtidx, grid = NB*16
  int qt = bx & 15, batch = bx >> 4;
  int nch = (qt + 2) >> 1;
  if (nch < 2) return;                  // flash wrote these directly
  int ps = 0;
  for (int j = 0; j < qt; ++j) ps += (j + 2) >> 1;
  int slot0 = batch * SLOTS_PB + ps;
  __shared__ float inv[256];
  int tid = threadIdx.x;
  {
    float L = 0.f;
    for (int c = 0; c < nch; ++c)
      L += lml[(size_t)(slot0 + c) * 256 + tid];
    inv[tid] = 1.f / fmaxf(L, 1e-30f);
  }
  __syncthreads();
  int isbf = *flagp;
  size_t obase = (size_t)batch * TT * HH + (size_t)qt * 256 * 128;
#pragma unroll 2
  for (int i = 0; i < 16; ++i) {
    int e8 = i * 256 + tid;             // bf16x8 index, 0..4095
    int row = e8 >> 4;
    float acc[8] = {};
    for (int c = 0; c < nch; ++c) {
      bf16x8 pv = *(const bf16x8*)(part + (size_t)(slot0 + c) * 32768 + (size_t)e8 * 8);
#pragma unroll
      for (int j = 0; j < 8; ++j) acc[j] += (float)pv[j];
    }
    float w = inv[row];
    if (isbf) {
      bf16x8 ob;
#pragma unroll
      for (int j = 0; j < 8; ++j) ob[j] = (__bf16)(acc[j] * w);
      *(bf16x8*)((__bf16*)out + obase + (size_t)e8 * 8) = ob;
    } else {
      float* o = (float*)out + obase + (size_t)e8 * 8;
#pragma unroll
      for (int j = 0; j < 8; ++j) o[j] = acc[j] * w;
    }
  }
}

extern "C" void kernel_launch(void* const* d_in, const int* in_sizes, int n_in,
                              void* d_out, int out_size, void* d_ws, size_t ws_size,
                              hipStream_t stream) {
  const void* x  = d_in[0];
  const void* Wq = d_in[1];
  const void* Wk = d_in[2];
  const void* Wv = d_in[3];
  char* wsb = (char*)d_ws;
  __bf16* q   = (__bf16*)wsb;
  __bf16* ktl = q   + (size_t)NB * TT * HH;
  __bf16* vtl = ktl + (size_t)NB * TT * HH;
  __bf16* wt  = vtl + (size_t)NB * TT * HH;
  size_t base = (((size_t)(3 * NB * TT * HH + 3 * CC * HH) * 2) + 255) & ~(size_t)255;
  int* flag = (int*)(wsb + base);
  float* lml = (float*)(wsb + base + 256);
  __bf16* part = (__bf16*)(wsb + base + 256 + (size_t)NB * SLOTS_PB * 256 * 4);

  detect_dtype<<<1, 64, 0, stream>>>((const unsigned int*)x, flag);
  transpose_w3<<<dim3(512, 3), 256, 0, stream>>>(Wq, Wk, Wv, wt, flag);
  qkv_proj<<<256, 768, 0, stream>>>(x, wt, q, ktl, vtl, flag);
  flash_attn<<<NB * 16 * 8, 256, 0, stream>>>(q, ktl, vtl, part, lml, d_out, flag);
  combine<<<NB * 16, 256, 0, stream>>>(part, lml, d_out, flag);
}